// Round 5
// baseline (1834.367 us; speedup 1.0000x reference)
//
#include <hip/hip_runtime.h>
#include <hip/hip_fp16.h>
#include <cstdint>
#include <cstddef>

#define BB 128
#define NN 1024
#define NI 64
#define TT 512
#define MAXNNZ 16384
#define NE 28
#define TH 16

// ws layout (bytes)
#define WS_OFFS   0u        // int[1025]
#define WS_CNT    8192u     // int[1024]
#define WS_IDX    16384u    // u16[MAXNNZ]
#define WS_VAL    65536u    // f32[MAXNNZ]
#define WS_PERM   131072u   // int[1024]
#define WS_IPERM  135168u   // int[1024]
#define WS_XSTATE 139264u   // f32[BB*NN] = 524288
#define WS_WINP   663552u   // f32[NI*NN] = 262144
#define WS_EIDX   925696u   // u16[NE*NN] = 57344
#define WS_WCNT   983040u   // int[16]
#define WS_U      1048576u  // fp16 U chunk [Tc][BB][NN]

// ---------- sparse build ----------
__global__ __launch_bounds__(64) void k_count(const float* __restrict__ W, int* __restrict__ cnt) {
    int col = blockIdx.x * 64 + threadIdx.x;
    int c = 0;
    for (int k = 0; k < NN; ++k) c += (W[(size_t)k * NN + col] != 0.0f) ? 1 : 0;
    cnt[col] = c;
}

__global__ __launch_bounds__(1024) void k_scan(const int* __restrict__ cnt, int* __restrict__ offs) {
    __shared__ int s[NN];
    int tid = threadIdx.x;
    s[tid] = cnt[tid];
    __syncthreads();
    for (int d = 1; d < NN; d <<= 1) {
        int v = (tid >= d) ? s[tid - d] : 0;
        __syncthreads();
        s[tid] += v;
        __syncthreads();
    }
    int incl = s[tid];
    offs[tid + 1] = (incl < MAXNNZ) ? incl : MAXNNZ;
    if (tid == 0) offs[0] = 0;
}

__global__ __launch_bounds__(64) void k_fill(const float* __restrict__ W, const int* __restrict__ offs,
                                             unsigned short* __restrict__ idx, float* __restrict__ val) {
    int col = blockIdx.x * 64 + threadIdx.x;
    int pos = offs[col];
    int end = offs[col + 1];
    for (int k = 0; k < NN; ++k) {
        float w = W[(size_t)k * NN + col];
        if (w != 0.0f) {
            if (pos < end) { idx[pos] = (unsigned short)k; val[pos] = w; ++pos; }
        }
    }
}

// rank columns by entry count (descending, stable) -> perm/iperm
__global__ __launch_bounds__(1024) void k_rank(const int* __restrict__ offs,
                                               int* __restrict__ perm, int* __restrict__ iperm) {
    __shared__ int sc[NN];
    int n = threadIdx.x;
    sc[n] = offs[n + 1] - offs[n];
    __syncthreads();
    int myc = sc[n];
    int r = 0;
    for (int m = 0; m < NN; ++m) {
        int cm = sc[m];
        r += (cm > myc || (cm == myc && m < n)) ? 1 : 0;
    }
    perm[r] = n;
    iperm[n] = r;
}

// Winp[i][r] = Win[i][perm[r]]  (rank-space input weights)
__global__ __launch_bounds__(256) void k_permwin(const float* __restrict__ Win, const int* __restrict__ perm,
                                                 float* __restrict__ Winp) {
    int idx = blockIdx.x * 256 + threadIdx.x;   // 65536 total
    int i = idx >> 10, r = idx & 1023;
    Winp[idx] = Win[(i << 10) + perm[r]];
}

// ---------- bank-aware gather schedule (deterministic greedy) ----------
// For each wave, assign each lane's entries to slots so each slot's 64 LDS
// addresses spread ~2/bank. Idle lanes get a donor lane's address (broadcast)
// with the 0x8000 flag -> weight 0 in k_step.
__global__ __launch_bounds__(1024) void k_sched(const int* __restrict__ offs,
        const unsigned short* __restrict__ gidx, const int* __restrict__ perm,
        const int* __restrict__ iperm, unsigned short* __restrict__ eidx,
        int* __restrict__ wcnt) {
    __shared__ unsigned int   spos[16][64][NE];  // (localidx<<16) | rank-space pos
    __shared__ int            so0[16][64];
    __shared__ unsigned short scnt[16][64];
    __shared__ unsigned short srem[16][64];
    __shared__ unsigned short sbank[16][32];
    int tid = threadIdx.x;
    int w = tid >> 6, l = tid & 63;
    int c = perm[tid];
    int o0 = offs[c];
    int cnt = offs[c + 1] - o0;
    if (cnt > NE) cnt = NE;
    so0[w][l] = o0;
    scnt[w][l] = (unsigned short)cnt;
    srem[w][l] = (unsigned short)cnt;
    for (int j = 0; j < cnt; ++j)
        spos[w][l][j] = (unsigned int)iperm[(int)gidx[o0 + j]] | ((unsigned int)j << 16);
    __syncthreads();
    if (tid < 16) {
        int wv = tid;
        int wmax = 0;
        for (int q = 0; q < 64; ++q) wmax = wmax > (int)scnt[wv][q] ? wmax : (int)scnt[wv][q];
        wcnt[wv] = wmax;
        for (int slot = 0; slot < wmax; ++slot) {
            for (int b = 0; b < 32; ++b) sbank[wv][b] = 0;
            int first_e = -1;
            unsigned long long assigned = 0ull;
            for (int lp = 0; lp < 64; ++lp) {
                int ln = (slot + lp) & 63;      // rotate start lane for fairness
                int rm = (int)srem[wv][ln];
                if (rm == 0) continue;
                int target = lp >> 5;           // allowed bank load for early exit
                int bestj = 0, bestload = 1 << 30;
                for (int j = 0; j < rm; ++j) {
                    int bk = (int)(spos[wv][ln][j] & 31u);
                    int ld = (int)sbank[wv][bk];
                    if (ld < bestload) { bestload = ld; bestj = j; if (ld <= target) break; }
                }
                unsigned int pe = spos[wv][ln][bestj];
                spos[wv][ln][bestj] = spos[wv][ln][rm - 1];   // compact
                srem[wv][ln] = (unsigned short)(rm - 1);
                sbank[wv][pe & 31u]++;
                int e = so0[wv][ln] + (int)(pe >> 16);
                eidx[slot * NN + wv * 64 + ln] = (unsigned short)e;
                if (first_e < 0) first_e = e;
                assigned |= (1ull << ln);
            }
            for (int ln = 0; ln < 64; ++ln)
                if (!((assigned >> ln) & 1ull))
                    eidx[slot * NN + wv * 64 + ln] = (unsigned short)(first_e | 0x8000);
        }
    }
}

// ---------- input projection into rank space, fp16 ----------
__global__ __launch_bounds__(256) void k_uproj(const float* __restrict__ In, const float* __restrict__ Winp,
                                               __half* __restrict__ U, int t0) {
    int tt = blockIdx.x >> 2;
    int bq = blockIdx.x & 3;
    int t  = t0 + tt;
    int b0 = bq * 32;
    __shared__ float s[32][NI];
    int tid = threadIdx.x;
    for (int q = tid; q < 32 * NI; q += 256) {
        int j = q >> 6, i = q & 63;
        s[j][i] = In[((size_t)(b0 + j) * NI + i) * TT + t];
    }
    __syncthreads();
    const float4* W4 = (const float4*)Winp;
    uint2* U2 = (uint2*)U;
    for (int bt = 0; bt < 32; bt += 8) {
        float4 acc[8];
#pragma unroll
        for (int j = 0; j < 8; ++j) acc[j] = make_float4(0.f, 0.f, 0.f, 0.f);
        for (int i = 0; i < NI; ++i) {
            float4 w = W4[i * (NN / 4) + tid];
#pragma unroll
            for (int j = 0; j < 8; ++j) {
                float sv = s[bt + j][i];
                acc[j].x = fmaf(w.x, sv, acc[j].x);
                acc[j].y = fmaf(w.y, sv, acc[j].y);
                acc[j].z = fmaf(w.z, sv, acc[j].z);
                acc[j].w = fmaf(w.w, sv, acc[j].w);
            }
        }
#pragma unroll
        for (int j = 0; j < 8; ++j) {
            float ax = fminf(fmaxf(acc[j].x, -60000.f), 60000.f);
            float ay = fminf(fmaxf(acc[j].y, -60000.f), 60000.f);
            float az = fminf(fmaxf(acc[j].z, -60000.f), 60000.f);
            float aw = fminf(fmaxf(acc[j].w, -60000.f), 60000.f);
            __half2 h01 = __floats2half2_rn(ax, ay);
            __half2 h23 = __floats2half2_rn(az, aw);
            uint2 pk;
            pk.x = *(unsigned int*)&h01;
            pk.y = *(unsigned int*)&h23;
            U2[((size_t)tt * BB + (b0 + bt + j)) * (NN / 4) + tid] = pk;
        }
    }
}

// ---------- recurrence ----------
__device__ __forceinline__ float fast_tanh(float z) {
    float a = fabsf(z) * 2.885390082f;       // 2*log2(e)
    a = fminf(a, 60.0f);
    float e = __builtin_amdgcn_exp2f(a);     // e^{2|z|}
    float r = 1.0f - __fdividef(2.0f, e + 1.0f);
    return z < 0.0f ? -r : r;
}

__global__ __launch_bounds__(1024) void k_step(const __half* __restrict__ U,
        const unsigned short* __restrict__ eidx, const unsigned short* __restrict__ gidx,
        const float* __restrict__ gval, const int* __restrict__ perm,
        const int* __restrict__ iperm, const int* __restrict__ wcnt,
        float* __restrict__ out, float* __restrict__ xstate, int t0, int Tc) {
    __shared__ float xbuf[2][NN];            // 8 KB ping-pong x (rank-indexed)
    int b = blockIdx.x, tid = threadIdx.x;
    int c = perm[tid];
    int wmax = wcnt[tid >> 6];

    float wv[NE];
    int ka[NE];
#pragma unroll
    for (int j = 0; j < NE; ++j) {
        if (j < wmax) {
            unsigned int v = eidx[j * NN + tid];
            int e = (int)(v & 0x7fffu);
            ka[j] = iperm[(int)gidx[e]] << 2;
            wv[j] = (v & 0x8000u) ? 0.0f : gval[e];
        } else { ka[j] = 0; wv[j] = 0.0f; }
    }

    float x = (t0 == 0) ? 0.0f : xstate[((size_t)b << 10) + tid];
    xbuf[0][tid] = x;
    __syncthreads();

    const char* xb = (const char*)&xbuf[0][0];
    const __half* Ub = U + (size_t)b * NN + tid;
    const size_t ustep = (size_t)BB * NN;
    float unx = __half2float(Ub[0]);

    for (int tb = 0; tb < Tc; tb += TH) {
        float xh[TH];
#pragma unroll
        for (int tt = 0; tt < TH; ++tt) {
            int t = tb + tt;
            float u = unx;
            if (t + 1 < Tc) unx = __half2float(Ub[(size_t)(t + 1) * ustep]);
            const int phr = (t & 1) << 12;
            float z0 = u, z1 = 0.f;
#pragma unroll
            for (int j = 0; j < NE; j += 2) {
                if (j < wmax)     z0 = fmaf(wv[j],     *(const float*)(xb + phr + ka[j]),     z0);
                if (j + 1 < wmax) z1 = fmaf(wv[j + 1], *(const float*)(xb + phr + ka[j + 1]), z1);
            }
            x = 0.5f * x + 0.5f * fast_tanh(z0 + z1);
            xh[tt] = x;
            ((float*)(xb + (phr ^ 4096)))[tid] = x;
            __syncthreads();
        }
        float4* op = (float4*)(out + ((size_t)b * NN + c) * TT + (size_t)(t0 + tb));
        op[0] = make_float4(xh[0],  xh[1],  xh[2],  xh[3]);
        op[1] = make_float4(xh[4],  xh[5],  xh[6],  xh[7]);
        op[2] = make_float4(xh[8],  xh[9],  xh[10], xh[11]);
        op[3] = make_float4(xh[12], xh[13], xh[14], xh[15]);
    }
    if (Tc < TT) xstate[((size_t)b << 10) + tid] = x;
}

extern "C" void kernel_launch(void* const* d_in, const int* in_sizes, int n_in,
                              void* d_out, int out_size, void* d_ws, size_t ws_size,
                              hipStream_t stream) {
    const float* In  = (const float*)d_in[0];
    const float* W   = (const float*)d_in[1];
    const float* Win = (const float*)d_in[2];
    float* out = (float*)d_out;
    char* ws = (char*)d_ws;
    int* offs           = (int*)(ws + WS_OFFS);
    int* cnt            = (int*)(ws + WS_CNT);
    unsigned short* idx = (unsigned short*)(ws + WS_IDX);
    float* val          = (float*)(ws + WS_VAL);
    int* perm           = (int*)(ws + WS_PERM);
    int* iperm          = (int*)(ws + WS_IPERM);
    float* xstate       = (float*)(ws + WS_XSTATE);
    float* Winp         = (float*)(ws + WS_WINP);
    unsigned short* eidx = (unsigned short*)(ws + WS_EIDX);
    int* wcnt           = (int*)(ws + WS_WCNT);
    __half* U           = (__half*)(ws + WS_U);

    // biggest U chunk (fp16) that fits in ws
    int Tc = 16;
    const int cands[6] = {512, 256, 128, 64, 32, 16};
    for (int i = 0; i < 6; ++i) {
        if ((size_t)WS_U + (size_t)cands[i] * BB * NN * 2 <= ws_size) { Tc = cands[i]; break; }
    }

    k_count<<<16, 64, 0, stream>>>(W, cnt);
    k_scan<<<1, 1024, 0, stream>>>(cnt, offs);
    k_fill<<<16, 64, 0, stream>>>(W, offs, idx, val);
    k_rank<<<1, 1024, 0, stream>>>(offs, perm, iperm);
    k_permwin<<<256, 256, 0, stream>>>(Win, perm, Winp);
    k_sched<<<1, 1024, 0, stream>>>(offs, idx, perm, iperm, eidx, wcnt);

    for (int t0 = 0; t0 < TT; t0 += Tc) {
        k_uproj<<<Tc * 4, 256, 0, stream>>>(In, Winp, U, t0);
        k_step<<<BB, 1024, 0, stream>>>(U, eidx, idx, val, perm, iperm, wcnt, out, xstate, t0, Tc);
    }
}

// Round 6
// 1069.620 us; speedup vs baseline: 1.7150x; 1.7150x over previous
//
#include <hip/hip_runtime.h>
#include <hip/hip_fp16.h>
#include <cstdint>
#include <cstddef>

#define BB 128
#define NN 1024
#define NI 64
#define TT 512
#define MAXNNZ 16384
#define NE 28
#define TH 16

// ws layout (bytes)
#define WS_OFFS   0u        // int[1025]
#define WS_CNT    8192u     // int[1024]
#define WS_IDX    16384u    // u16[MAXNNZ]
#define WS_VAL    65536u    // f32[MAXNNZ]
#define WS_PERM   131072u   // int[1024]
#define WS_IPERM  135168u   // int[1024]
#define WS_WINPH  139264u   // fp16[NI*NN] = 131072
#define WS_INH    270336u   // fp16[BB*NI*TT] = 8388608

typedef _Float16 f16x8 __attribute__((ext_vector_type(8)));
typedef float f32x4 __attribute__((ext_vector_type(4)));

// ---------- sparse build ----------
__global__ __launch_bounds__(64) void k_count(const float* __restrict__ W, int* __restrict__ cnt) {
    int col = blockIdx.x * 64 + threadIdx.x;
    int c = 0;
    for (int k = 0; k < NN; ++k) c += (W[(size_t)k * NN + col] != 0.0f) ? 1 : 0;
    cnt[col] = c;
}

__global__ __launch_bounds__(1024) void k_scan(const int* __restrict__ cnt, int* __restrict__ offs) {
    __shared__ int s[NN];
    int tid = threadIdx.x;
    s[tid] = cnt[tid];
    __syncthreads();
    for (int d = 1; d < NN; d <<= 1) {
        int v = (tid >= d) ? s[tid - d] : 0;
        __syncthreads();
        s[tid] += v;
        __syncthreads();
    }
    int incl = s[tid];
    offs[tid + 1] = (incl < MAXNNZ) ? incl : MAXNNZ;
    if (tid == 0) offs[0] = 0;
}

__global__ __launch_bounds__(64) void k_fill(const float* __restrict__ W, const int* __restrict__ offs,
                                             unsigned short* __restrict__ idx, float* __restrict__ val) {
    int col = blockIdx.x * 64 + threadIdx.x;
    int pos = offs[col];
    int end = offs[col + 1];
    for (int k = 0; k < NN; ++k) {
        float w = W[(size_t)k * NN + col];
        if (w != 0.0f) {
            if (pos < end) { idx[pos] = (unsigned short)k; val[pos] = w; ++pos; }
        }
    }
}

// rank columns by entry count (descending, stable) -> perm/iperm
__global__ __launch_bounds__(1024) void k_rank(const int* __restrict__ offs,
                                               int* __restrict__ perm, int* __restrict__ iperm) {
    __shared__ int sc[NN];
    int n = threadIdx.x;
    sc[n] = offs[n + 1] - offs[n];
    __syncthreads();
    int myc = sc[n];
    int r = 0;
    for (int m = 0; m < NN; ++m) {
        int cm = sc[m];
        r += (cm > myc || (cm == myc && m < n)) ? 1 : 0;
    }
    perm[r] = n;
    iperm[n] = r;
}

// Winph[i][r] = fp16(Win[i][perm[r]])  (rank-space input weights, fp16)
__global__ __launch_bounds__(256) void k_permwinh(const float* __restrict__ Win, const int* __restrict__ perm,
                                                  __half* __restrict__ Winph) {
    int idx = blockIdx.x * 256 + threadIdx.x;   // 65536 total
    int i = idx >> 10, rr = idx & 1023;
    Winph[idx] = __float2half(Win[(i << 10) + perm[rr]]);
}

// Inh = fp16(In), vectorized
__global__ __launch_bounds__(256) void k_inh(const float* __restrict__ In, __half* __restrict__ Inh) {
    int i = blockIdx.x * 256 + threadIdx.x;     // over float4 elements: BB*NI*TT/4 = 1048576
    float4 v = ((const float4*)In)[i];
    __half2 h01 = __floats2half2_rn(v.x, v.y);
    __half2 h23 = __floats2half2_rn(v.z, v.w);
    uint2 pk;
    pk.x = *(unsigned int*)&h01;
    pk.y = *(unsigned int*)&h23;
    ((uint2*)Inh)[i] = pk;
}

// ---------- recurrence (one launch, all 512 steps, fused MFMA input projection) ----------
__device__ __forceinline__ float fast_tanh(float z) {
    float a = fabsf(z) * 2.885390082f;       // 2*log2(e)
    a = fminf(a, 60.0f);
    float e = __builtin_amdgcn_exp2f(a);     // e^{2|z|}
    float r = 1.0f - __fdividef(2.0f, e + 1.0f);
    return z < 0.0f ? -r : r;
}

__global__ __launch_bounds__(1024, 4) void k_step(const _Float16* __restrict__ Inh,
        const _Float16* __restrict__ Winph,
        const int* __restrict__ offs, const unsigned short* __restrict__ gidx,
        const float* __restrict__ gval, const int* __restrict__ perm,
        const int* __restrict__ iperm, float* __restrict__ out) {
    __shared__ float xbuf[2][NN];            // 8 KB ping-pong x (rank-indexed)
    __shared__ _Float16 Ut[2][TH][NN];       // 64 KB double-buffered input projection
    int b = blockIdx.x, tid = threadIdx.x;
    int c = perm[tid];                       // this thread's column (rank-sorted)
    int lane = tid & 63, w = tid >> 6;
    int r = lane & 15, q = lane >> 4;
    int wbase = w * 64;

    // ---- sparse gather lists (byte offsets packed u16x2) ----
    int o0 = offs[c];
    int cnt = offs[c + 1] - o0;
    float wv[NE];
    unsigned int ka2[NE / 2];
#pragma unroll
    for (int jp = 0; jp < NE / 2; ++jp) {
        int e0 = o0 + 2 * jp, e1 = e0 + 1;
        unsigned lo = (2 * jp     < cnt) ? (unsigned)(iperm[(int)gidx[e0]] << 2) : 0u;
        unsigned hi = (2 * jp + 1 < cnt) ? (unsigned)(iperm[(int)gidx[e1]] << 2) : 0u;
        ka2[jp] = lo | (hi << 16);
        wv[2 * jp]     = (2 * jp     < cnt) ? gval[e0] : 0.0f;
        wv[2 * jp + 1] = (2 * jp + 1 < cnt) ? gval[e1] : 0.0f;
    }
    int wmax = cnt;
#pragma unroll
    for (int d = 1; d < 64; d <<= 1) {
        int o = __shfl_xor(wmax, d);
        wmax = wmax > o ? wmax : o;
    }
    wmax = __builtin_amdgcn_readfirstlane(wmax);

    // ---- static B fragments: Winph chunk for this wave's 64 columns ----
    // mfma_f32_16x16x32_f16 B layout: col = lane&15, k = (lane>>4)*8 + j
    f16x8 bf[4][2];
#pragma unroll
    for (int nt = 0; nt < 4; ++nt)
#pragma unroll
        for (int kh = 0; kh < 2; ++kh)
#pragma unroll
            for (int j = 0; j < 8; ++j)
                bf[nt][kh][j] = Winph[(size_t)(kh * 32 + 8 * q + j) * NN + wbase + nt * 16 + r];

    const _Float16* inh = Inh + (size_t)b * NI * TT;   // [i][t]

    // compute Ut tile starting at t1 into buffer nbuf
    auto computeU = [&](int t1, int nbuf) {
        // A layout: row(t) = lane&15, k(i) = (lane>>4)*8 + j
        f16x8 a0, a1;
#pragma unroll
        for (int j = 0; j < 8; ++j) {
            a0[j] = inh[(size_t)(8 * q + j) * TT + t1 + r];
            a1[j] = inh[(size_t)(32 + 8 * q + j) * TT + t1 + r];
        }
#pragma unroll
        for (int nt = 0; nt < 4; ++nt) {
            f32x4 acc = {0.f, 0.f, 0.f, 0.f};
            acc = __builtin_amdgcn_mfma_f32_16x16x32_f16(a0, bf[nt][0], acc, 0, 0, 0);
            acc = __builtin_amdgcn_mfma_f32_16x16x32_f16(a1, bf[nt][1], acc, 0, 0, 0);
            // C layout: col = lane&15 (n), row = (lane>>4)*4 + r4 (t)
#pragma unroll
            for (int r4 = 0; r4 < 4; ++r4)
                Ut[nbuf][q * 4 + r4][wbase + nt * 16 + r] = (_Float16)acc[r4];
        }
    };

    float x = 0.0f;
    xbuf[0][tid] = 0.0f;
    computeU(0, 0);                          // prologue: tile 0
    __syncthreads();

    const char* xb = (const char*)&xbuf[0][0];

    for (int tile = 0; tile < TT / TH; ++tile) {
        int tb = tile * TH;
        if (tile + 1 < TT / TH) computeU(tb + TH, (tile + 1) & 1);  // produce next tile
        const int ub = tile & 1;
        float xh[TH];
#pragma unroll
        for (int tt = 0; tt < TH; ++tt) {
            int t = tb + tt;
            float u = (float)Ut[ub][tt][tid];
            const int phr = (t & 1) << 12;
            float z0 = u, z1 = 0.f;
#pragma unroll
            for (int jp = 0; jp < NE / 2; ++jp) {
                if (2 * jp < wmax)
                    z0 = fmaf(wv[2 * jp],     *(const float*)(xb + phr + (ka2[jp] & 0xffffu)), z0);
                if (2 * jp + 1 < wmax)
                    z1 = fmaf(wv[2 * jp + 1], *(const float*)(xb + phr + (ka2[jp] >> 16)),     z1);
            }
            x = 0.5f * x + 0.5f * fast_tanh(z0 + z1);
            xh[tt] = x;
            ((float*)(xb + (phr ^ 4096)))[tid] = x;
            __syncthreads();
        }
        // dump 16 steps: 64 B contiguous per thread
        float4* op = (float4*)(out + ((size_t)b * NN + c) * TT + (size_t)tb);
        op[0] = make_float4(xh[0],  xh[1],  xh[2],  xh[3]);
        op[1] = make_float4(xh[4],  xh[5],  xh[6],  xh[7]);
        op[2] = make_float4(xh[8],  xh[9],  xh[10], xh[11]);
        op[3] = make_float4(xh[12], xh[13], xh[14], xh[15]);
    }
}

extern "C" void kernel_launch(void* const* d_in, const int* in_sizes, int n_in,
                              void* d_out, int out_size, void* d_ws, size_t ws_size,
                              hipStream_t stream) {
    const float* In  = (const float*)d_in[0];
    const float* W   = (const float*)d_in[1];
    const float* Win = (const float*)d_in[2];
    float* out = (float*)d_out;
    char* ws = (char*)d_ws;
    int* offs           = (int*)(ws + WS_OFFS);
    int* cnt            = (int*)(ws + WS_CNT);
    unsigned short* idx = (unsigned short*)(ws + WS_IDX);
    float* val          = (float*)(ws + WS_VAL);
    int* perm           = (int*)(ws + WS_PERM);
    int* iperm          = (int*)(ws + WS_IPERM);
    __half* Winph       = (__half*)(ws + WS_WINPH);
    __half* Inh         = (__half*)(ws + WS_INH);

    k_count<<<16, 64, 0, stream>>>(W, cnt);
    k_scan<<<1, 1024, 0, stream>>>(cnt, offs);
    k_fill<<<16, 64, 0, stream>>>(W, offs, idx, val);
    k_rank<<<1, 1024, 0, stream>>>(offs, perm, iperm);
    k_permwinh<<<256, 256, 0, stream>>>(Win, perm, Winph);
    k_inh<<<(BB * NI * TT / 4 + 255) / 256, 256, 0, stream>>>(In, Inh);
    k_step<<<BB, 1024, 0, stream>>>((const _Float16*)Inh, (const _Float16*)Winph,
                                    offs, idx, val, perm, iperm, out);
}

// Round 7
// 1065.465 us; speedup vs baseline: 1.7217x; 1.0039x over previous
//
#include <hip/hip_runtime.h>
#include <hip/hip_fp16.h>
#include <cstdint>
#include <cstddef>

#define BB 128
#define NN 1024
#define NI 64
#define TT 512
#define MAXNNZ 16384
#define NE 32
#define TH 16

// ws layout (bytes)
#define WS_OFFS   0u         // int[1025]
#define WS_CNT    8192u      // int[1024]
#define WS_IDX    16384u     // u16[MAXNNZ]
#define WS_VAL    65536u     // f32[MAXNNZ]
#define WS_XSTATE 131072u    // f32[BB*NN] = 524288
#define WS_INT    655360u    // f32 In^T [BB][TT][NI] = 16777216
#define WS_U      17432576u  // fp16 U chunk [Tc][BB][NN]

// ---------- sparse build ----------
__global__ __launch_bounds__(64) void k_count(const float* __restrict__ W, int* __restrict__ cnt) {
    int col = blockIdx.x * 64 + threadIdx.x;
    int c = 0;
    for (int k = 0; k < NN; ++k) c += (W[(size_t)k * NN + col] != 0.0f) ? 1 : 0;
    cnt[col] = c;
}

__global__ __launch_bounds__(1024) void k_scan(const int* __restrict__ cnt, int* __restrict__ offs) {
    __shared__ int s[NN];
    int tid = threadIdx.x;
    s[tid] = cnt[tid];
    __syncthreads();
    for (int d = 1; d < NN; d <<= 1) {
        int v = (tid >= d) ? s[tid - d] : 0;
        __syncthreads();
        s[tid] += v;
        __syncthreads();
    }
    int incl = s[tid];
    offs[tid + 1] = (incl < MAXNNZ) ? incl : MAXNNZ;
    if (tid == 0) offs[0] = 0;
}

__global__ __launch_bounds__(64) void k_fill(const float* __restrict__ W, const int* __restrict__ offs,
                                             unsigned short* __restrict__ idx, float* __restrict__ val) {
    int col = blockIdx.x * 64 + threadIdx.x;
    int pos = offs[col];
    int end = offs[col + 1];
    for (int k = 0; k < NN; ++k) {
        float w = W[(size_t)k * NN + col];
        if (w != 0.0f) {
            if (pos < end) { idx[pos] = (unsigned short)k; val[pos] = w; ++pos; }
        }
    }
}

// ---------- In transpose: Int[b][t][i] = In[b][i][t] ----------
__global__ __launch_bounds__(256) void k_trans(const float* __restrict__ In, float* __restrict__ Int) {
    int b = blockIdx.x >> 3;
    int tq = blockIdx.x & 7;
    int t0 = tq * 64;
    __shared__ float ts[64][65];
    int tid = threadIdx.x;
    for (int q = tid; q < 64 * 16; q += 256) {
        int i = q >> 4, j = q & 15;
        float4 v = *(const float4*)(In + ((size_t)b * NI + i) * TT + t0 + 4 * j);
        ts[i][4 * j + 0] = v.x; ts[i][4 * j + 1] = v.y;
        ts[i][4 * j + 2] = v.z; ts[i][4 * j + 3] = v.w;
    }
    __syncthreads();
    for (int q = tid; q < 64 * 16; q += 256) {
        int tc = q >> 4, j = q & 15;
        float4 v = make_float4(ts[4 * j + 0][tc], ts[4 * j + 1][tc],
                               ts[4 * j + 2][tc], ts[4 * j + 3][tc]);
        *(float4*)(Int + ((size_t)b * TT + t0 + tc) * NI + 4 * j) = v;
    }
}

// ---------- input projection from In^T: U[tc][b][n] fp16 ----------
__global__ __launch_bounds__(256) void k_uproj2(const float* __restrict__ Int, const float* __restrict__ Win,
                                                __half* __restrict__ U, int t0c, int Tc) {
    int nblk = Tc / 32;
    int b  = blockIdx.x / nblk;
    int tq = blockIdx.x % nblk;
    int t0 = t0c + tq * 32;
    __shared__ float s[32][NI];      // 8 KB
    int tid = threadIdx.x;
    for (int q = tid; q < 32 * 16; q += 256) {
        int tt = q >> 4, j = q & 15;
        float4 v = *(const float4*)(Int + ((size_t)b * TT + t0 + tt) * NI + 4 * j);
        s[tt][4 * j + 0] = v.x; s[tt][4 * j + 1] = v.y;
        s[tt][4 * j + 2] = v.z; s[tt][4 * j + 3] = v.w;
    }
    __syncthreads();
    const float4* W4 = (const float4*)Win;
    uint2* U2 = (uint2*)U;
    for (int th = 0; th < 2; ++th) {
        float4 acc[16];
#pragma unroll
        for (int t = 0; t < 16; ++t) acc[t] = make_float4(0.f, 0.f, 0.f, 0.f);
        for (int i = 0; i < NI; ++i) {
            float4 w = W4[(size_t)i * 256 + tid];
#pragma unroll
            for (int t = 0; t < 16; ++t) {
                float sv = s[th * 16 + t][i];
                acc[t].x = fmaf(w.x, sv, acc[t].x);
                acc[t].y = fmaf(w.y, sv, acc[t].y);
                acc[t].z = fmaf(w.z, sv, acc[t].z);
                acc[t].w = fmaf(w.w, sv, acc[t].w);
            }
        }
#pragma unroll
        for (int t = 0; t < 16; ++t) {
            float ax = fminf(fmaxf(acc[t].x, -60000.f), 60000.f);
            float ay = fminf(fmaxf(acc[t].y, -60000.f), 60000.f);
            float az = fminf(fmaxf(acc[t].z, -60000.f), 60000.f);
            float aw = fminf(fmaxf(acc[t].w, -60000.f), 60000.f);
            __half2 h01 = __floats2half2_rn(ax, ay);
            __half2 h23 = __floats2half2_rn(az, aw);
            uint2 pk;
            pk.x = *(unsigned int*)&h01;
            pk.y = *(unsigned int*)&h23;
            U2[((size_t)(t0 - t0c + th * 16 + t) * BB + b) * 256 + tid] = pk;
        }
    }
}

// ---------- recurrence ----------
__device__ __forceinline__ float fast_tanh(float z) {
    float a = fabsf(z) * 2.885390082f;       // 2*log2(e)
    a = fminf(a, 60.0f);
    float e = __builtin_amdgcn_exp2f(a);     // e^{2|z|}
    float r = 1.0f - __fdividef(2.0f, e + 1.0f);
    return z < 0.0f ? -r : r;
}

__global__ __launch_bounds__(1024, 4) __attribute__((amdgpu_waves_per_eu(4, 4)))
void k_step(const _Float16* __restrict__ U,
            const int* __restrict__ offs, const unsigned short* __restrict__ gidx,
            const float* __restrict__ gval, float* __restrict__ out,
            float* __restrict__ xstate, int t0, int Tc) {
    __shared__ float xbuf[2][NN];            // 8 KB ping-pong x
    int b = blockIdx.x, n = threadIdx.x;

    // gather tables fully in registers (VGPR cap 128 via waves_per_eu(4,4))
    int o0 = offs[n];
    int cnt = offs[n + 1] - o0;
    float wv[NE];
    int ka[NE];
#pragma unroll
    for (int j = 0; j < NE; ++j) {
        if (j < cnt) { wv[j] = gval[o0 + j]; ka[j] = ((int)gidx[o0 + j]) << 2; }
        else         { wv[j] = 0.0f;         ka[j] = 0; }
    }
    int wmax = cnt;
#pragma unroll
    for (int d = 1; d < 64; d <<= 1) {
        int o = __shfl_xor(wmax, d);
        wmax = wmax > o ? wmax : o;
    }
    wmax = __builtin_amdgcn_readfirstlane(wmax);

    float x = (t0 == 0) ? 0.0f : xstate[((size_t)b << 10) + n];
    xbuf[0][n] = x;
    __syncthreads();

    const char* xb = (const char*)&xbuf[0][0];
    const _Float16* Ub = U + (size_t)b * NN + n;
    const size_t ustep = (size_t)BB * NN;
    float unx = (float)Ub[0];

    for (int tb = 0; tb < Tc; tb += TH) {
        float xh[TH];
#pragma unroll
        for (int tt = 0; tt < TH; ++tt) {
            int t = tb + tt;
            float u = unx;
            if (t + 1 < Tc) unx = (float)Ub[(size_t)(t + 1) * ustep];
            const int phr = (t & 1) << 12;
            float z0 = u, z1 = 0.f, z2 = 0.f, z3 = 0.f;
#pragma unroll
            for (int j = 0; j < NE; j += 4) {
                if (j < wmax)     z0 = fmaf(wv[j],     *(const float*)(xb + phr + ka[j]),     z0);
                if (j + 1 < wmax) z1 = fmaf(wv[j + 1], *(const float*)(xb + phr + ka[j + 1]), z1);
                if (j + 2 < wmax) z2 = fmaf(wv[j + 2], *(const float*)(xb + phr + ka[j + 2]), z2);
                if (j + 3 < wmax) z3 = fmaf(wv[j + 3], *(const float*)(xb + phr + ka[j + 3]), z3);
            }
            x = 0.5f * x + 0.5f * fast_tanh((z0 + z1) + (z2 + z3));
            xh[tt] = x;
            ((float*)(xb + (phr ^ 4096)))[n] = x;
            __syncthreads();
        }
        float4* op = (float4*)(out + ((size_t)b * NN + n) * TT + (size_t)(t0 + tb));
        op[0] = make_float4(xh[0],  xh[1],  xh[2],  xh[3]);
        op[1] = make_float4(xh[4],  xh[5],  xh[6],  xh[7]);
        op[2] = make_float4(xh[8],  xh[9],  xh[10], xh[11]);
        op[3] = make_float4(xh[12], xh[13], xh[14], xh[15]);
    }
    if (Tc < TT) xstate[((size_t)b << 10) + n] = x;
}

extern "C" void kernel_launch(void* const* d_in, const int* in_sizes, int n_in,
                              void* d_out, int out_size, void* d_ws, size_t ws_size,
                              hipStream_t stream) {
    const float* In  = (const float*)d_in[0];
    const float* W   = (const float*)d_in[1];
    const float* Win = (const float*)d_in[2];
    float* out = (float*)d_out;
    char* ws = (char*)d_ws;
    int* offs           = (int*)(ws + WS_OFFS);
    int* cnt            = (int*)(ws + WS_CNT);
    unsigned short* idx = (unsigned short*)(ws + WS_IDX);
    float* val          = (float*)(ws + WS_VAL);
    float* xstate       = (float*)(ws + WS_XSTATE);
    float* Int          = (float*)(ws + WS_INT);
    __half* U           = (__half*)(ws + WS_U);

    // biggest fp16 U chunk that fits in ws
    int Tc = 32;
    const int cands[5] = {512, 256, 128, 64, 32};
    for (int i = 0; i < 5; ++i) {
        if ((size_t)WS_U + (size_t)cands[i] * BB * NN * 2 <= ws_size) { Tc = cands[i]; break; }
    }

    k_count<<<16, 64, 0, stream>>>(W, cnt);
    k_scan<<<1, 1024, 0, stream>>>(cnt, offs);
    k_fill<<<16, 64, 0, stream>>>(W, offs, idx, val);
    k_trans<<<BB * 8, 256, 0, stream>>>(In, Int);

    for (int t0 = 0; t0 < TT; t0 += Tc) {
        k_uproj2<<<BB * (Tc / 32), 256, 0, stream>>>(Int, Win, U, t0, Tc);
        k_step<<<BB, 1024, 0, stream>>>((const _Float16*)U, offs, idx, val, out, xstate, t0, Tc);
    }
}

// Round 8
// 951.990 us; speedup vs baseline: 1.9269x; 1.1192x over previous
//
#include <hip/hip_runtime.h>
#include <cstdint>
#include <cstddef>

#define BB 128
#define NN 1024
#define NI 64
#define TT 512
#define MAXNNZ 16384
#define TH 8

// ws layout (bytes)
#define WS_OFFS   0u         // int[1025]
#define WS_CNT    8192u      // int[1024]
#define WS_IDX    16384u     // u16[MAXNNZ]
#define WS_VAL    65536u     // f32[MAXNNZ]
#define WS_XSTATE 131072u    // f32[BB*NN]
#define WS_U      1048576u   // f32 U chunk [Tc][BB][NN]

// ---------- sparse build ----------
__global__ __launch_bounds__(64) void k_count(const float* __restrict__ W, int* __restrict__ cnt) {
    int col = blockIdx.x * 64 + threadIdx.x;
    int c = 0;
    for (int k = 0; k < NN; ++k) c += (W[(size_t)k * NN + col] != 0.0f) ? 1 : 0;
    cnt[col] = c;
}

__global__ __launch_bounds__(1024) void k_scan(const int* __restrict__ cnt, int* __restrict__ offs) {
    __shared__ int s[NN];
    int tid = threadIdx.x;
    s[tid] = cnt[tid];
    __syncthreads();
    for (int d = 1; d < NN; d <<= 1) {
        int v = (tid >= d) ? s[tid - d] : 0;
        __syncthreads();
        s[tid] += v;
        __syncthreads();
    }
    int incl = s[tid];
    offs[tid + 1] = (incl < MAXNNZ) ? incl : MAXNNZ;
    if (tid == 0) offs[0] = 0;
}

__global__ __launch_bounds__(64) void k_fill(const float* __restrict__ W, const int* __restrict__ offs,
                                             unsigned short* __restrict__ idx, float* __restrict__ val) {
    int col = blockIdx.x * 64 + threadIdx.x;
    int pos = offs[col];
    int end = offs[col + 1];
    for (int k = 0; k < NN; ++k) {
        float w = W[(size_t)k * NN + col];
        if (w != 0.0f) {
            if (pos < end) { idx[pos] = (unsigned short)k; val[pos] = w; ++pos; }
        }
    }
}

// ---------- input projection: U[t][b][n] = sum_i In[b][i][t] * Win[i][n], fp32 ----------
__global__ __launch_bounds__(256) void k_uproj3(const float* __restrict__ In, const float* __restrict__ Win,
                                                float* __restrict__ U, int t0c, int nblk) {
    int b  = blockIdx.x / nblk;
    int tq = blockIdx.x % nblk;
    int t0 = t0c + tq * 32;                    // global start t of this 32-tile
    __shared__ float s[32][NI + 1];            // s[t][i], padded
    int tid = threadIdx.x;
    {
        int i = tid >> 2, g = tid & 3;
        const float* ip = In + ((size_t)b * NI + i) * TT + t0 + g * 8;
        float4 v0 = *(const float4*)(ip);
        float4 v1 = *(const float4*)(ip + 4);
        s[g * 8 + 0][i] = v0.x; s[g * 8 + 1][i] = v0.y;
        s[g * 8 + 2][i] = v0.z; s[g * 8 + 3][i] = v0.w;
        s[g * 8 + 4][i] = v1.x; s[g * 8 + 5][i] = v1.y;
        s[g * 8 + 6][i] = v1.z; s[g * 8 + 7][i] = v1.w;
    }
    __syncthreads();
    const float4* W4 = (const float4*)Win;     // [i][n/4]
    float4* U4 = (float4*)U;
    for (int th = 0; th < 2; ++th) {
        float4 acc[16];
#pragma unroll
        for (int t = 0; t < 16; ++t) acc[t] = make_float4(0.f, 0.f, 0.f, 0.f);
        for (int i = 0; i < NI; ++i) {
            float4 w = W4[(size_t)i * 256 + tid];
#pragma unroll
            for (int t = 0; t < 16; ++t) {
                float sv = s[th * 16 + t][i];
                acc[t].x = fmaf(w.x, sv, acc[t].x);
                acc[t].y = fmaf(w.y, sv, acc[t].y);
                acc[t].z = fmaf(w.z, sv, acc[t].z);
                acc[t].w = fmaf(w.w, sv, acc[t].w);
            }
        }
#pragma unroll
        for (int t = 0; t < 16; ++t)
            U4[((size_t)(tq * 32 + th * 16 + t) * BB + b) * 256 + tid] = acc[t];
    }
}

// ---------- recurrence ----------
__device__ __forceinline__ float fast_tanh(float z) {
    float a = fabsf(z) * 2.885390082f;       // 2*log2(e)
    a = fminf(a, 60.0f);
    float e = __builtin_amdgcn_exp2f(a);     // e^{2|z|}
    float r = 1.0f - __fdividef(2.0f, e + 1.0f);
    return z < 0.0f ? -r : r;
}

// 28 entries, round-robin over 4 accumulators
#define L28(M) \
  M(0,0) M(1,1) M(2,2) M(3,3) M(4,0) M(5,1) M(6,2) M(7,3) \
  M(8,0) M(9,1) M(10,2) M(11,3) M(12,0) M(13,1) M(14,2) M(15,3) \
  M(16,0) M(17,1) M(18,2) M(19,3) M(20,0) M(21,1) M(22,2) M(23,3) \
  M(24,0) M(25,1) M(26,2) M(27,3)

#define DW(i,zk)  float w##i; int a##i;
#define IW(i,zk)  if (cnt > i) { w##i = gval[o0 + i]; a##i = ((int)gidx[o0 + i]) << 2; } \
                  else         { w##i = 0.0f;         a##i = 0; }
#define GLD(i,zk)  float g##i = *(const float*)(xp + a##i);
#define GFMA(i,zk) z##zk = fmaf(w##i, g##i, z##zk);

// one recurrence step; PH = compile-time read-phase byte offset (0 or 4096)
#define STEP(PH, XDST) { \
    float u = unx; \
    int tn = t + 1; tn = (tn < Tc) ? tn : (Tc - 1); \
    unx = Ub[(size_t)tn * ustep]; \
    const char* xp = xb + (PH); \
    L28(GLD) \
    float z0 = u, z1 = 0.f, z2 = 0.f, z3 = 0.f; \
    L28(GFMA) \
    x = 0.5f * x + 0.5f * fast_tanh((z0 + z1) + (z2 + z3)); \
    XDST = x; \
    ((float*)(xb + ((PH) ^ 4096)))[n] = x; \
    __syncthreads(); \
    ++t; \
}

__global__ __launch_bounds__(1024, 4)
void k_step(const float* __restrict__ U,
            const int* __restrict__ offs, const unsigned short* __restrict__ gidx,
            const float* __restrict__ gval, float* __restrict__ out,
            float* __restrict__ xstate, int t0, int Tc) {
    __shared__ float xbuf[2][NN];            // 8 KB ping-pong x
    int b = blockIdx.x, n = threadIdx.x;

    int o0 = offs[n];
    int cnt = offs[n + 1] - o0;
    L28(DW)
    L28(IW)

    float x = (t0 == 0) ? 0.0f : xstate[((size_t)b << 10) + n];
    xbuf[0][n] = x;
    __syncthreads();

    char* xb = (char*)&xbuf[0][0];
    const float* Ub = U + (size_t)b * NN + n;
    const size_t ustep = (size_t)BB * NN;
    float unx = Ub[0];

    for (int tb = 0; tb < Tc; tb += TH) {
        int t = tb;
        float y0, y1, y2, y3, y4, y5, y6, y7;
        STEP(0,    y0)
        STEP(4096, y1)
        STEP(0,    y2)
        STEP(4096, y3)
        STEP(0,    y4)
        STEP(4096, y5)
        STEP(0,    y6)
        STEP(4096, y7)
        float4* op = (float4*)(out + ((size_t)b * NN + n) * TT + (size_t)(t0 + tb));
        op[0] = make_float4(y0, y1, y2, y3);
        op[1] = make_float4(y4, y5, y6, y7);
    }
    if (Tc < TT) xstate[((size_t)b << 10) + n] = x;
}

extern "C" void kernel_launch(void* const* d_in, const int* in_sizes, int n_in,
                              void* d_out, int out_size, void* d_ws, size_t ws_size,
                              hipStream_t stream) {
    const float* In  = (const float*)d_in[0];
    const float* W   = (const float*)d_in[1];
    const float* Win = (const float*)d_in[2];
    float* out = (float*)d_out;
    char* ws = (char*)d_ws;
    int* offs           = (int*)(ws + WS_OFFS);
    int* cnt            = (int*)(ws + WS_CNT);
    unsigned short* idx = (unsigned short*)(ws + WS_IDX);
    float* val          = (float*)(ws + WS_VAL);
    float* xstate       = (float*)(ws + WS_XSTATE);
    float* U            = (float*)(ws + WS_U);

    // biggest fp32 U chunk that fits in ws
    int Tc = 32;
    const int cands[5] = {512, 256, 128, 64, 32};
    for (int i = 0; i < 5; ++i) {
        if ((size_t)WS_U + (size_t)cands[i] * BB * NN * 4 <= ws_size) { Tc = cands[i]; break; }
    }

    k_count<<<16, 64, 0, stream>>>(W, cnt);
    k_scan<<<1, 1024, 0, stream>>>(cnt, offs);
    k_fill<<<16, 64, 0, stream>>>(W, offs, idx, val);

    for (int t0 = 0; t0 < TT; t0 += Tc) {
        int nblk = Tc / 32;
        k_uproj3<<<BB * nblk, 256, 0, stream>>>(In, Win, U, t0, nblk);
        k_step<<<BB, 1024, 0, stream>>>(U, offs, idx, val, out, xstate, t0, Tc);
    }
}